// Round 1
// baseline (1250.503 us; speedup 1.0000x reference)
//
#include <hip/hip_runtime.h>
#include <math.h>

#define NN 50000
#define NE 800000
#define FDIM 128
#define CLS 40

// ---------------- CSR build ----------------

__global__ void zero_k(int* degi, int* cnt, int* fill) {
    int i = blockIdx.x * blockDim.x + threadIdx.x;
    if (i < NN) { degi[i] = 0; cnt[i] = 0; fill[i] = 0; }
}

__global__ void count_k(const int* __restrict__ esrc, const int* __restrict__ edst,
                        int* degi, int* cnt) {
    int e = blockIdx.x * blockDim.x + threadIdx.x;
    if (e < NE) {
        atomicAdd(&degi[esrc[e]], 1);
        atomicAdd(&cnt[edst[e]], 1);
    }
}

__global__ void dinv_k(const int* __restrict__ degi, float* __restrict__ dinv) {
    int i = blockIdx.x * blockDim.x + threadIdx.x;
    if (i < NN) {
        int d = degi[i];
        dinv[i] = (d > 0) ? rsqrtf((float)d) : 0.0f;
    }
}

#define SCAN_CHUNK 2048
#define SCAN_NB ((NN + SCAN_CHUNK - 1) / SCAN_CHUNK)   // 25

__global__ void scanA_k(const int* __restrict__ cnt, int* __restrict__ bsum) {
    __shared__ int lds[256];
    int base = blockIdx.x * SCAN_CHUNK;
    int s = 0;
    for (int j = threadIdx.x; j < SCAN_CHUNK; j += 256) {
        int i = base + j;
        if (i < NN) s += cnt[i];
    }
    lds[threadIdx.x] = s;
    __syncthreads();
    for (int off = 128; off > 0; off >>= 1) {
        if (threadIdx.x < off) lds[threadIdx.x] += lds[threadIdx.x + off];
        __syncthreads();
    }
    if (threadIdx.x == 0) bsum[blockIdx.x] = lds[0];
}

__global__ void scanB_k(int* bsum, int* rp) {
    if (threadIdx.x == 0 && blockIdx.x == 0) {
        int run = 0;
        for (int b = 0; b < SCAN_NB; b++) { int t = bsum[b]; bsum[b] = run; run += t; }
        rp[NN] = run;  // == NE
    }
}

__global__ void scanC_k(const int* __restrict__ cnt, const int* __restrict__ bsum,
                        int* __restrict__ rp) {
    __shared__ int lds[256];
    int base = blockIdx.x * SCAN_CHUNK + threadIdx.x * 8;
    int v[8];
    int s = 0;
    #pragma unroll
    for (int j = 0; j < 8; j++) {
        int i = base + j;
        v[j] = (i < NN) ? cnt[i] : 0;
        s += v[j];
    }
    lds[threadIdx.x] = s;
    __syncthreads();
    for (int off = 1; off < 256; off <<= 1) {
        int t = (threadIdx.x >= (unsigned)off) ? lds[threadIdx.x - off] : 0;
        __syncthreads();
        lds[threadIdx.x] += t;
        __syncthreads();
    }
    int incl = lds[threadIdx.x];
    int excl = incl - s;
    int run = bsum[blockIdx.x] + excl;
    #pragma unroll
    for (int j = 0; j < 8; j++) {
        int i = base + j;
        if (i < NN) rp[i] = run;
        run += v[j];
    }
}

__global__ void scatter_k(const int* __restrict__ esrc, const int* __restrict__ edst,
                          const int* __restrict__ rp, int* fill,
                          const float* __restrict__ dinv,
                          int* __restrict__ csrc, float* __restrict__ cw) {
    int e = blockIdx.x * blockDim.x + threadIdx.x;
    if (e < NE) {
        int s = esrc[e], d = edst[e];
        int pos = rp[d] + atomicAdd(&fill[d], 1);
        csrc[pos] = s;
        cw[pos] = -dinv[s] * dinv[d];
    }
}

// ---------------- SpMM: out[row] = (CHEB? 2*lhat - prev : lhat) ----------------
// 32 threads per row (4 feats each as float4), 8 rows per 256-thread block.

template <bool CHEB>
__global__ __launch_bounds__(256) void spmm_k(const float* __restrict__ T,
                                              const float* __restrict__ prev,
                                              float* __restrict__ outb,
                                              const int* __restrict__ rp,
                                              const int* __restrict__ csrc,
                                              const float* __restrict__ cw) {
    int row = blockIdx.x * 8 + (threadIdx.x >> 5);
    if (row >= NN) return;
    int lane = threadIdx.x & 31;
    int e0 = rp[row], e1 = rp[row + 1];
    float4 acc = make_float4(0.f, 0.f, 0.f, 0.f);
    for (int e = e0; e < e1; e++) {
        int s = csrc[e];
        float w = cw[e];
        float4 t = *(const float4*)&T[(size_t)s * FDIM + lane * 4];
        acc.x += w * t.x; acc.y += w * t.y; acc.z += w * t.z; acc.w += w * t.w;
    }
    float4 r;
    if (CHEB) {
        float4 p = *(const float4*)&prev[(size_t)row * FDIM + lane * 4];
        r.x = 2.f * acc.x - p.x;
        r.y = 2.f * acc.y - p.y;
        r.z = 2.f * acc.z - p.z;
        r.w = 2.f * acc.w - p.w;
    } else {
        r = acc;
    }
    *(float4*)&outb[(size_t)row * FDIM + lane * 4] = r;
}

// ---------------- GEMM: out[N x HOUT] (+)= A[N x 128] @ W[128 x HOUT] ----------------
// W staged in LDS (padded to HOUTP cols). 64-row tiles, 256 threads.

template <int HOUTP, int HOUT, bool ACCUM>
__global__ __launch_bounds__(256, 2) void gemm_k(const float* __restrict__ A,
                                                 const float* __restrict__ W,
                                                 const float* __restrict__ bias,
                                                 float* __restrict__ outb) {
    constexpr int NC = HOUTP / 4;   // col groups of 4
    constexpr int RG = 256 / NC;    // row groups
    constexpr int RPT = 64 / RG;    // rows per thread
    __shared__ float Wlds[128 * HOUTP];

    if (HOUT == HOUTP) {
        const float4* Wv = (const float4*)W;
        float4* Lv = (float4*)Wlds;
        for (int i = threadIdx.x; i < 128 * HOUTP / 4; i += 256) Lv[i] = Wv[i];
    } else {
        for (int i = threadIdx.x; i < 128 * HOUTP; i += 256) {
            int r = i / HOUTP, c = i % HOUTP;
            Wlds[i] = (c < HOUT) ? W[r * HOUT + c] : 0.0f;
        }
    }
    __syncthreads();

    int tc = threadIdx.x % NC;
    int tr = threadIdx.x / NC;
    int row0 = blockIdx.x * 64;

    float4 acc[RPT];
    #pragma unroll
    for (int i = 0; i < RPT; i++) acc[i] = make_float4(0.f, 0.f, 0.f, 0.f);

    #pragma unroll 4
    for (int k0 = 0; k0 < 128; k0 += 4) {
        float4 w0 = *(const float4*)&Wlds[(k0 + 0) * HOUTP + tc * 4];
        float4 w1 = *(const float4*)&Wlds[(k0 + 1) * HOUTP + tc * 4];
        float4 w2 = *(const float4*)&Wlds[(k0 + 2) * HOUTP + tc * 4];
        float4 w3 = *(const float4*)&Wlds[(k0 + 3) * HOUTP + tc * 4];
        #pragma unroll
        for (int i = 0; i < RPT; i++) {
            int r = row0 + tr + RG * i;
            int rc = (r < NN) ? r : (NN - 1);  // clamp; store guarded in epilogue
            float4 a = *(const float4*)&A[(size_t)rc * FDIM + k0];
            acc[i].x += a.x * w0.x + a.y * w1.x + a.z * w2.x + a.w * w3.x;
            acc[i].y += a.x * w0.y + a.y * w1.y + a.z * w2.y + a.w * w3.y;
            acc[i].z += a.x * w0.z + a.y * w1.z + a.z * w2.z + a.w * w3.z;
            acc[i].w += a.x * w0.w + a.y * w1.w + a.z * w2.w + a.w * w3.w;
        }
    }

    if (HOUT != HOUTP && tc * 4 >= HOUT) return;
    #pragma unroll
    for (int i = 0; i < RPT; i++) {
        int r = row0 + tr + RG * i;
        if (r >= NN) continue;
        float* op = &outb[(size_t)r * HOUT + tc * 4];
        float4 o;
        if (ACCUM) {
            o = *(const float4*)op;
            o.x += acc[i].x; o.y += acc[i].y; o.z += acc[i].z; o.w += acc[i].w;
        } else {
            float4 b = *(const float4*)&bias[tc * 4];
            o.x = acc[i].x + b.x; o.y = acc[i].y + b.y;
            o.z = acc[i].z + b.z; o.w = acc[i].w + b.w;
        }
        *(float4*)op = o;
    }
}

// ---------------- elementwise ----------------

__global__ void relu_k(const float* __restrict__ in, float* __restrict__ outb) {
    int i = blockIdx.x * blockDim.x + threadIdx.x;
    if (i < NN * FDIM / 4) {
        float4 v = ((const float4*)in)[i];
        v.x = fmaxf(v.x, 0.f); v.y = fmaxf(v.y, 0.f);
        v.z = fmaxf(v.z, 0.f); v.w = fmaxf(v.w, 0.f);
        ((float4*)outb)[i] = v;
    }
}

__global__ __launch_bounds__(256) void lsm_k(float* __restrict__ io) {
    int row = blockIdx.x * 4 + (threadIdx.x >> 6);
    if (row >= NN) return;
    int lane = threadIdx.x & 63;
    float v = (lane < CLS) ? io[(size_t)row * CLS + lane] : -INFINITY;
    float m = v;
    for (int off = 32; off; off >>= 1) m = fmaxf(m, __shfl_xor(m, off));
    float e = (lane < CLS) ? __expf(v - m) : 0.0f;
    float sum = e;
    for (int off = 32; off; off >>= 1) sum += __shfl_xor(sum, off);
    float ls = logf(sum);
    if (lane < CLS) io[(size_t)row * CLS + lane] = v - m - ls;
}

// ---------------- launch ----------------

extern "C" void kernel_launch(void* const* d_in, const int* in_sizes, int n_in,
                              void* d_out, int out_size, void* d_ws, size_t ws_size,
                              hipStream_t stream) {
    const float* x    = (const float*)d_in[0];
    const int*   esrc = (const int*)d_in[1];
    const int*   edst = (const int*)d_in[2];
    const float* W0   = (const float*)d_in[3];
    const float* b0   = (const float*)d_in[4];
    const float* W1   = (const float*)d_in[5];
    const float* b1   = (const float*)d_in[6];
    const float* W2   = (const float*)d_in[7];
    const float* b2   = (const float*)d_in[8];
    float* out = (float*)d_out;

    char* p = (char*)d_ws;
    auto alloc = [&](size_t bytes) -> void* {
        void* r = (void*)p;
        p += (bytes + 255) & ~(size_t)255;
        return r;
    };
    float* hbuf = (float*)alloc((size_t)NN * FDIM * 4);
    float* Bb   = (float*)alloc((size_t)NN * FDIM * 4);
    float* Cb   = (float*)alloc((size_t)NN * FDIM * 4);
    float* o128 = (float*)alloc((size_t)NN * FDIM * 4);
    int*   degi = (int*)alloc(NN * 4);
    int*   cnt  = (int*)alloc(NN * 4);
    int*   fill = (int*)alloc(NN * 4);
    float* dinv = (float*)alloc(NN * 4);
    int*   rp   = (int*)alloc((NN + 1) * 4);
    int*   bsum = (int*)alloc(SCAN_NB * 4);
    int*   csrc = (int*)alloc((size_t)NE * 4);
    float* cw   = (float*)alloc((size_t)NE * 4);

    const int TB = 256;
    int gN = (NN + TB - 1) / TB;        // 196
    int gE = (NE + TB - 1) / TB;        // 3125

    // Build CSR (by dst) + edge weights
    zero_k<<<gN, TB, 0, stream>>>(degi, cnt, fill);
    count_k<<<gE, TB, 0, stream>>>(esrc, edst, degi, cnt);
    dinv_k<<<gN, TB, 0, stream>>>(degi, dinv);
    scanA_k<<<SCAN_NB, TB, 0, stream>>>(cnt, bsum);
    scanB_k<<<1, 64, 0, stream>>>(bsum, rp);
    scanC_k<<<SCAN_NB, TB, 0, stream>>>(cnt, bsum, rp);
    scatter_k<<<gE, TB, 0, stream>>>(esrc, edst, rp, fill, dinv, csrc, cw);

    int gGemm = (NN + 63) / 64;         // 782
    int gSpmm = (NN + 7) / 8;           // 6250
    int gRelu = NN * FDIM / 4 / TB;     // 6250
    int gLsm  = (NN + 3) / 4;           // 12500

    for (int l = 0; l < 3; l++) {
        const float* X = (l == 0) ? x : hbuf;
        const float* Wl = (l == 0) ? W0 : (l == 1) ? W1 : W2;
        const float* bl = (l == 0) ? b0 : (l == 1) ? b1 : b2;
        if (l < 2) {
            const int ks = 128 * 128;
            // out = Tx0 @ W[0] + b
            gemm_k<128, 128, false><<<gGemm, TB, 0, stream>>>(X, Wl + 0 * ks, bl, o128);
            // Tx1 = lhat(Tx0)
            spmm_k<false><<<gSpmm, TB, 0, stream>>>(X, nullptr, Bb, rp, csrc, cw);
            gemm_k<128, 128, true><<<gGemm, TB, 0, stream>>>(Bb, Wl + 1 * ks, bl, o128);
            // Tx2 = 2*lhat(Tx1) - Tx0
            spmm_k<true><<<gSpmm, TB, 0, stream>>>(Bb, X, Cb, rp, csrc, cw);
            gemm_k<128, 128, true><<<gGemm, TB, 0, stream>>>(Cb, Wl + 2 * ks, bl, o128);
            // Tx3 = 2*lhat(Tx2) - Tx1  (in-place into Bb)
            spmm_k<true><<<gSpmm, TB, 0, stream>>>(Cb, Bb, Bb, rp, csrc, cw);
            gemm_k<128, 128, true><<<gGemm, TB, 0, stream>>>(Bb, Wl + 3 * ks, bl, o128);
            // h = relu(out)
            relu_k<<<gRelu, TB, 0, stream>>>(o128, hbuf);
        } else {
            const int ks = 128 * CLS;
            gemm_k<64, CLS, false><<<gGemm, TB, 0, stream>>>(X, Wl + 0 * ks, bl, out);
            spmm_k<false><<<gSpmm, TB, 0, stream>>>(X, nullptr, Bb, rp, csrc, cw);
            gemm_k<64, CLS, true><<<gGemm, TB, 0, stream>>>(Bb, Wl + 1 * ks, bl, out);
            spmm_k<true><<<gSpmm, TB, 0, stream>>>(Bb, X, Cb, rp, csrc, cw);
            gemm_k<64, CLS, true><<<gGemm, TB, 0, stream>>>(Cb, Wl + 2 * ks, bl, out);
            spmm_k<true><<<gSpmm, TB, 0, stream>>>(Cb, Bb, Bb, rp, csrc, cw);
            gemm_k<64, CLS, true><<<gGemm, TB, 0, stream>>>(Bb, Wl + 3 * ks, bl, out);
            lsm_k<<<gLsm, TB, 0, stream>>>(out);
        }
    }
}

// Round 2
// 593.636 us; speedup vs baseline: 2.1065x; 2.1065x over previous
//
#include <hip/hip_runtime.h>
#include <math.h>

#define NN 50000
#define NE 800000
#define FDIM 128
#define CLS 40
#define AW 512   // fused A width: 4 Chebyshev slices of 128

typedef __attribute__((ext_vector_type(8))) short short8v;
typedef __attribute__((ext_vector_type(8))) unsigned short ushort8v;
typedef __attribute__((ext_vector_type(4))) float f32x4;

__device__ inline float b2f(unsigned short u) {
    union { unsigned int i; float f; } v; v.i = ((unsigned)u) << 16; return v.f;
}
__device__ inline unsigned short f2b(float f) {
    unsigned int x = __float_as_uint(f);
    unsigned int r = (x + 0x7fffu + ((x >> 16) & 1u)) >> 16;
    return (unsigned short)r;
}

// ---------------- CSR build ----------------

__global__ void zero_k(int* degi, int* cnt, int* fill) {
    int i = blockIdx.x * blockDim.x + threadIdx.x;
    if (i < NN) { degi[i] = 0; cnt[i] = 0; fill[i] = 0; }
}

__global__ void count_k(const int* __restrict__ esrc, const int* __restrict__ edst,
                        int* degi, int* cnt) {
    int e = blockIdx.x * blockDim.x + threadIdx.x;
    if (e < NE) {
        atomicAdd(&degi[esrc[e]], 1);
        atomicAdd(&cnt[edst[e]], 1);
    }
}

__global__ void dinv_k(const int* __restrict__ degi, float* __restrict__ dinv) {
    int i = blockIdx.x * blockDim.x + threadIdx.x;
    if (i < NN) {
        int d = degi[i];
        dinv[i] = (d > 0) ? rsqrtf((float)d) : 0.0f;
    }
}

#define SCAN_CHUNK 2048
#define SCAN_NB ((NN + SCAN_CHUNK - 1) / SCAN_CHUNK)   // 25

__global__ void scanA_k(const int* __restrict__ cnt, int* __restrict__ bsum) {
    __shared__ int lds[256];
    int base = blockIdx.x * SCAN_CHUNK;
    int s = 0;
    for (int j = threadIdx.x; j < SCAN_CHUNK; j += 256) {
        int i = base + j;
        if (i < NN) s += cnt[i];
    }
    lds[threadIdx.x] = s;
    __syncthreads();
    for (int off = 128; off > 0; off >>= 1) {
        if (threadIdx.x < off) lds[threadIdx.x] += lds[threadIdx.x + off];
        __syncthreads();
    }
    if (threadIdx.x == 0) bsum[blockIdx.x] = lds[0];
}

__global__ void scanB_k(int* bsum, int* rp) {
    if (threadIdx.x == 0 && blockIdx.x == 0) {
        int run = 0;
        for (int b = 0; b < SCAN_NB; b++) { int t = bsum[b]; bsum[b] = run; run += t; }
        rp[NN] = run;  // == NE
    }
}

__global__ void scanC_k(const int* __restrict__ cnt, const int* __restrict__ bsum,
                        int* __restrict__ rp) {
    __shared__ int lds[256];
    int base = blockIdx.x * SCAN_CHUNK + threadIdx.x * 8;
    int v[8];
    int s = 0;
    #pragma unroll
    for (int j = 0; j < 8; j++) {
        int i = base + j;
        v[j] = (i < NN) ? cnt[i] : 0;
        s += v[j];
    }
    lds[threadIdx.x] = s;
    __syncthreads();
    for (int off = 1; off < 256; off <<= 1) {
        int t = (threadIdx.x >= (unsigned)off) ? lds[threadIdx.x - off] : 0;
        __syncthreads();
        lds[threadIdx.x] += t;
        __syncthreads();
    }
    int incl = lds[threadIdx.x];
    int excl = incl - s;
    int run = bsum[blockIdx.x] + excl;
    #pragma unroll
    for (int j = 0; j < 8; j++) {
        int i = base + j;
        if (i < NN) rp[i] = run;
        run += v[j];
    }
}

__global__ void scatter_k(const int* __restrict__ esrc, const int* __restrict__ edst,
                          const int* __restrict__ rp, int* fill,
                          const float* __restrict__ dinv,
                          int2* __restrict__ ew) {
    int e = blockIdx.x * blockDim.x + threadIdx.x;
    if (e < NE) {
        int s = esrc[e], d = edst[e];
        int pos = rp[d] + atomicAdd(&fill[d], 1);
        int2 v;
        v.x = s;
        v.y = __float_as_int(-dinv[s] * dinv[d]);
        ew[pos] = v;
    }
}

// ---------------- conversions / weight prep ----------------

__global__ void cvtx_k(const float* __restrict__ x, unsigned short* __restrict__ Ab) {
    int i = blockIdx.x * blockDim.x + threadIdx.x;  // NN*16 groups of 8 feats
    if (i >= NN * 16) return;
    int row = i >> 4, cg = i & 15;
    const float4* xp = (const float4*)(x + (size_t)row * FDIM + cg * 8);
    float4 v0 = xp[0], v1 = xp[1];
    ushort8v r;
    r[0] = f2b(v0.x); r[1] = f2b(v0.y); r[2] = f2b(v0.z); r[3] = f2b(v0.w);
    r[4] = f2b(v1.x); r[5] = f2b(v1.y); r[6] = f2b(v1.z); r[7] = f2b(v1.w);
    *(ushort8v*)(Ab + (size_t)row * AW + cg * 8) = r;
}

// Wt[n][kk*128 + r] = W[kk][r][n]  (bf16, column-major weights for fragment loads)
__global__ void wprep_k(const float* __restrict__ W, unsigned short* __restrict__ Wt,
                        int hout, int npad) {
    int i = blockIdx.x * blockDim.x + threadIdx.x;  // npad*512
    if (i >= npad * AW) return;
    int n = i >> 9, k = i & (AW - 1);
    int kk = k >> 7, r = k & 127;
    float v = (n < hout) ? W[(size_t)kk * 128 * hout + (size_t)r * hout + n] : 0.0f;
    Wt[i] = f2b(v);
}

// ---------------- SpMM (bf16 gather, fp32 accum) ----------------
// 16 lanes per row (8 bf16 each = 16B), 16 rows per 256-thread block.

template <bool CHEB>
__global__ __launch_bounds__(256) void spmm_k(const unsigned short* __restrict__ inp,
                                              const unsigned short* __restrict__ prevp,
                                              unsigned short* __restrict__ outp,
                                              const int* __restrict__ rp,
                                              const int2* __restrict__ ew) {
    int row = blockIdx.x * 16 + (threadIdx.x >> 4);
    if (row >= NN) return;
    int ln = threadIdx.x & 15;
    int e0 = rp[row], e1 = rp[row + 1];
    float acc[8] = {0.f, 0.f, 0.f, 0.f, 0.f, 0.f, 0.f, 0.f};
    int e = e0;
    for (; e + 2 <= e1; e += 2) {
        int2 m0 = ew[e];
        int2 m1 = ew[e + 1];
        ushort8v t0 = *(const ushort8v*)(inp + (size_t)m0.x * AW + ln * 8);
        ushort8v t1 = *(const ushort8v*)(inp + (size_t)m1.x * AW + ln * 8);
        float w0 = __int_as_float(m0.y), w1 = __int_as_float(m1.y);
        #pragma unroll
        for (int j = 0; j < 8; j++) acc[j] += w0 * b2f(t0[j]);
        #pragma unroll
        for (int j = 0; j < 8; j++) acc[j] += w1 * b2f(t1[j]);
    }
    if (e < e1) {
        int2 m0 = ew[e];
        ushort8v t0 = *(const ushort8v*)(inp + (size_t)m0.x * AW + ln * 8);
        float w0 = __int_as_float(m0.y);
        #pragma unroll
        for (int j = 0; j < 8; j++) acc[j] += w0 * b2f(t0[j]);
    }
    ushort8v r;
    if (CHEB) {
        ushort8v p = *(const ushort8v*)(prevp + (size_t)row * AW + ln * 8);
        #pragma unroll
        for (int j = 0; j < 8; j++) r[j] = f2b(2.f * acc[j] - b2f(p[j]));
    } else {
        #pragma unroll
        for (int j = 0; j < 8; j++) r[j] = f2b(acc[j]);
    }
    *(ushort8v*)(outp + (size_t)row * AW + ln * 8) = r;
}

// ---------------- MFMA GEMM ----------------
// C[N x HOUT] = A[N x 512](bf16) @ Wt^T + bias.
// Wt is [HOUT_pad][512] (weights col-major so fragments are contiguous loads).
// Block: 256 thr = 4 waves, 64 rows; wave = 16 rows x full HOUT.
// NOTE: A and B fragments use the SAME lane->k mapping (k = k0 + (lane>>4)*8 + j),
// so any bijective k-permutation of the true HW fragment layout cancels.

__global__ __launch_bounds__(256) void gemm_hid_k(const unsigned short* __restrict__ A,
                                                  const unsigned short* __restrict__ Wt,
                                                  const float* __restrict__ bias,
                                                  unsigned short* __restrict__ Hout) {
    int w = threadIdx.x >> 6;
    int lane = threadIdx.x & 63;
    int ln = lane & 15, gp = lane >> 4;
    int rowbase = blockIdx.x * 64 + w * 16;
    if (rowbase >= NN) return;   // NN % 16 == 0, so full tiles only
    const unsigned short* Arow = A + (size_t)(rowbase + ln) * AW + gp * 8;
    const unsigned short* Wrow = Wt + (size_t)ln * AW + gp * 8;

    f32x4 acc[8];
    #pragma unroll
    for (int i = 0; i < 8; i++) acc[i] = (f32x4){0.f, 0.f, 0.f, 0.f};

    #pragma unroll 2
    for (int k0 = 0; k0 < AW; k0 += 32) {
        short8v a = *(const short8v*)(Arow + k0);
        #pragma unroll
        for (int nt = 0; nt < 8; nt++) {
            short8v b = *(const short8v*)(Wrow + (size_t)nt * 16 * AW + k0);
            acc[nt] = __builtin_amdgcn_mfma_f32_16x16x32_bf16(a, b, acc[nt], 0, 0, 0);
        }
    }

    #pragma unroll
    for (int nt = 0; nt < 8; nt++) {
        int col = nt * 16 + ln;
        float bv = bias[col];
        #pragma unroll
        for (int j = 0; j < 4; j++) {
            int r = rowbase + gp * 4 + j;
            float v = fmaxf(acc[nt][j] + bv, 0.0f);
            Hout[(size_t)r * AW + col] = f2b(v);
        }
    }
}

__global__ __launch_bounds__(256) void gemm_out_k(const unsigned short* __restrict__ A,
                                                  const unsigned short* __restrict__ Wt,
                                                  const float* __restrict__ bias,
                                                  float* __restrict__ outb) {
    int w = threadIdx.x >> 6;
    int lane = threadIdx.x & 63;
    int ln = lane & 15, gp = lane >> 4;
    int rowbase = blockIdx.x * 64 + w * 16;
    if (rowbase >= NN) return;
    const unsigned short* Arow = A + (size_t)(rowbase + ln) * AW + gp * 8;
    const unsigned short* Wrow = Wt + (size_t)ln * AW + gp * 8;

    f32x4 acc[3];
    #pragma unroll
    for (int i = 0; i < 3; i++) acc[i] = (f32x4){0.f, 0.f, 0.f, 0.f};

    #pragma unroll 2
    for (int k0 = 0; k0 < AW; k0 += 32) {
        short8v a = *(const short8v*)(Arow + k0);
        #pragma unroll
        for (int nt = 0; nt < 3; nt++) {
            short8v b = *(const short8v*)(Wrow + (size_t)nt * 16 * AW + k0);
            acc[nt] = __builtin_amdgcn_mfma_f32_16x16x32_bf16(a, b, acc[nt], 0, 0, 0);
        }
    }

    #pragma unroll
    for (int nt = 0; nt < 3; nt++) {
        int col = nt * 16 + ln;
        if (col < CLS) {
            float bv = bias[col];
            #pragma unroll
            for (int j = 0; j < 4; j++) {
                int r = rowbase + gp * 4 + j;
                outb[(size_t)r * CLS + col] = acc[nt][j] + bv;
            }
        }
    }
}

// ---------------- log_softmax ----------------

__global__ __launch_bounds__(256) void lsm_k(float* __restrict__ io) {
    int row = blockIdx.x * 4 + (threadIdx.x >> 6);
    if (row >= NN) return;
    int lane = threadIdx.x & 63;
    float v = (lane < CLS) ? io[(size_t)row * CLS + lane] : -INFINITY;
    float m = v;
    for (int off = 32; off; off >>= 1) m = fmaxf(m, __shfl_xor(m, off));
    float e = (lane < CLS) ? __expf(v - m) : 0.0f;
    float sum = e;
    for (int off = 32; off; off >>= 1) sum += __shfl_xor(sum, off);
    float ls = logf(sum);
    if (lane < CLS) io[(size_t)row * CLS + lane] = v - m - ls;
}

// ---------------- launch ----------------

extern "C" void kernel_launch(void* const* d_in, const int* in_sizes, int n_in,
                              void* d_out, int out_size, void* d_ws, size_t ws_size,
                              hipStream_t stream) {
    const float* x    = (const float*)d_in[0];
    const int*   esrc = (const int*)d_in[1];
    const int*   edst = (const int*)d_in[2];
    const float* W0   = (const float*)d_in[3];
    const float* b0   = (const float*)d_in[4];
    const float* W1   = (const float*)d_in[5];
    const float* b1   = (const float*)d_in[6];
    const float* W2   = (const float*)d_in[7];
    const float* b2   = (const float*)d_in[8];
    float* out = (float*)d_out;

    char* p = (char*)d_ws;
    auto alloc = [&](size_t bytes) -> void* {
        void* r = (void*)p;
        p += (bytes + 255) & ~(size_t)255;
        return r;
    };
    unsigned short* Abuf = (unsigned short*)alloc((size_t)NN * AW * 2);   // 51.2 MB
    unsigned short* Wt0  = (unsigned short*)alloc((size_t)128 * AW * 2);
    unsigned short* Wt1  = (unsigned short*)alloc((size_t)128 * AW * 2);
    unsigned short* Wt2  = (unsigned short*)alloc((size_t)48 * AW * 2);
    int*   degi = (int*)alloc(NN * 4);
    int*   cnt  = (int*)alloc(NN * 4);
    int*   fill = (int*)alloc(NN * 4);
    float* dinv = (float*)alloc(NN * 4);
    int*   rp   = (int*)alloc((NN + 1) * 4);
    int*   bsum = (int*)alloc(SCAN_NB * 4);
    int2*  ew   = (int2*)alloc((size_t)NE * 8);

    const int TB = 256;
    int gN = (NN + TB - 1) / TB;
    int gE = (NE + TB - 1) / TB;

    // CSR build (by dst) + packed edge (src, weight)
    zero_k<<<gN, TB, 0, stream>>>(degi, cnt, fill);
    count_k<<<gE, TB, 0, stream>>>(esrc, edst, degi, cnt);
    dinv_k<<<gN, TB, 0, stream>>>(degi, dinv);
    scanA_k<<<SCAN_NB, TB, 0, stream>>>(cnt, bsum);
    scanB_k<<<1, 64, 0, stream>>>(bsum, rp);
    scanC_k<<<SCAN_NB, TB, 0, stream>>>(cnt, bsum, rp);
    scatter_k<<<gE, TB, 0, stream>>>(esrc, edst, rp, fill, dinv, ew);

    // x -> bf16 slice 0 ; weight prep
    cvtx_k<<<(NN * 16 + TB - 1) / TB, TB, 0, stream>>>(x, Abuf);
    wprep_k<<<(128 * AW + TB - 1) / TB, TB, 0, stream>>>(W0, Wt0, 128, 128);
    wprep_k<<<(128 * AW + TB - 1) / TB, TB, 0, stream>>>(W1, Wt1, 128, 128);
    wprep_k<<<(48 * AW + TB - 1) / TB, TB, 0, stream>>>(W2, Wt2, CLS, 48);

    int gSpmm = (NN + 15) / 16;   // 3125
    int gGemm = (NN + 63) / 64;   // 782
    int gLsm  = (NN + 3) / 4;

    unsigned short* s0 = Abuf + 0 * 128;
    unsigned short* s1 = Abuf + 1 * 128;
    unsigned short* s2 = Abuf + 2 * 128;
    unsigned short* s3 = Abuf + 3 * 128;

    for (int l = 0; l < 3; l++) {
        // Chebyshev recurrence into slices 1..3 (slice 0 = h)
        spmm_k<false><<<gSpmm, TB, 0, stream>>>(s0, nullptr, s1, rp, ew);
        spmm_k<true><<<gSpmm, TB, 0, stream>>>(s1, s0, s2, rp, ew);
        spmm_k<true><<<gSpmm, TB, 0, stream>>>(s2, s1, s3, rp, ew);
        if (l < 2) {
            const unsigned short* Wt = (l == 0) ? Wt0 : Wt1;
            const float* bl = (l == 0) ? b0 : b1;
            gemm_hid_k<<<gGemm, TB, 0, stream>>>(Abuf, Wt, bl, Abuf);  // writes relu'd h into slice 0
        } else {
            gemm_out_k<<<gGemm, TB, 0, stream>>>(Abuf, Wt2, b2, out);
            lsm_k<<<gLsm, TB, 0, stream>>>(out);
        }
    }
}

// Round 4
// 465.254 us; speedup vs baseline: 2.6878x; 1.2759x over previous
//
#include <hip/hip_runtime.h>
#include <math.h>

#define NN 50000
#define NE 800000
#define FDIM 128
#define CLS 40
#define AW 512   // fused A width: 4 Chebyshev slices of 128

typedef __attribute__((ext_vector_type(8))) short short8v;
typedef __attribute__((ext_vector_type(8))) unsigned short ushort8v;
typedef __attribute__((ext_vector_type(4))) float f32x4;

__device__ inline float b2f(unsigned short u) {
    union { unsigned int i; float f; } v; v.i = ((unsigned)u) << 16; return v.f;
}
__device__ inline unsigned short f2b(float f) {
    unsigned int x = __float_as_uint(f);
    unsigned int r = (x + 0x7fffu + ((x >> 16) & 1u)) >> 16;
    return (unsigned short)r;
}

// ---------------- CSR build ----------------

__global__ void zero_k(int* degi, int* cnt) {
    int i = blockIdx.x * blockDim.x + threadIdx.x;
    if (i < NN) { degi[i] = 0; cnt[i] = 0; }
}

__global__ void count_k(const int4* __restrict__ esrc, const int4* __restrict__ edst,
                        int* degi, int* cnt) {
    int e = blockIdx.x * blockDim.x + threadIdx.x;
    if (e < NE / 4) {
        int4 s = esrc[e], d = edst[e];
        atomicAdd(&degi[s.x], 1); atomicAdd(&degi[s.y], 1);
        atomicAdd(&degi[s.z], 1); atomicAdd(&degi[s.w], 1);
        atomicAdd(&cnt[d.x], 1); atomicAdd(&cnt[d.y], 1);
        atomicAdd(&cnt[d.z], 1); atomicAdd(&cnt[d.w], 1);
    }
}

__global__ void dinv_k(const int* __restrict__ degi, float* __restrict__ dinv) {
    int i = blockIdx.x * blockDim.x + threadIdx.x;
    if (i < NN) {
        int d = degi[i];
        dinv[i] = (d > 0) ? rsqrtf((float)d) : 0.0f;
    }
}

#define SCAN_CHUNK 2048
#define SCAN_NB ((NN + SCAN_CHUNK - 1) / SCAN_CHUNK)   // 25

__global__ void scanA_k(const int* __restrict__ cnt, int* __restrict__ bsum) {
    __shared__ int lds[256];
    int base = blockIdx.x * SCAN_CHUNK;
    int s = 0;
    for (int j = threadIdx.x; j < SCAN_CHUNK; j += 256) {
        int i = base + j;
        if (i < NN) s += cnt[i];
    }
    lds[threadIdx.x] = s;
    __syncthreads();
    for (int off = 128; off > 0; off >>= 1) {
        if (threadIdx.x < off) lds[threadIdx.x] += lds[threadIdx.x + off];
        __syncthreads();
    }
    if (threadIdx.x == 0) bsum[blockIdx.x] = lds[0];
}

__global__ void scanB_k(int* bsum, int* rp) {
    if (threadIdx.x == 0 && blockIdx.x == 0) {
        int run = 0;
        for (int b = 0; b < SCAN_NB; b++) { int t = bsum[b]; bsum[b] = run; run += t; }
        rp[NN] = run;  // == NE
    }
}

__global__ void scanC_k(const int* __restrict__ cnt, const int* __restrict__ bsum,
                        int* __restrict__ rp) {
    __shared__ int lds[256];
    int base = blockIdx.x * SCAN_CHUNK + threadIdx.x * 8;
    int v[8];
    int s = 0;
    #pragma unroll
    for (int j = 0; j < 8; j++) {
        int i = base + j;
        v[j] = (i < NN) ? cnt[i] : 0;
        s += v[j];
    }
    lds[threadIdx.x] = s;
    __syncthreads();
    for (int off = 1; off < 256; off <<= 1) {
        int t = (threadIdx.x >= (unsigned)off) ? lds[threadIdx.x - off] : 0;
        __syncthreads();
        lds[threadIdx.x] += t;
        __syncthreads();
    }
    int incl = lds[threadIdx.x];
    int excl = incl - s;
    int run = bsum[blockIdx.x] + excl;
    #pragma unroll
    for (int j = 0; j < 8; j++) {
        int i = base + j;
        if (i < NN) rp[i] = run;
        run += v[j];
    }
}

// scatter: pos = rp[d] + (--cnt[d])  (cnt destroyed; order within row arbitrary)
__global__ void scatter_k(const int* __restrict__ esrc, const int* __restrict__ edst,
                          const int* __restrict__ rp, int* cnt,
                          const float* __restrict__ dinv,
                          int2* __restrict__ ew) {
    int e = blockIdx.x * blockDim.x + threadIdx.x;
    if (e < NE) {
        int s = esrc[e], d = edst[e];
        int pos = rp[d] + atomicSub(&cnt[d], 1) - 1;
        int2 v;
        v.x = s;
        v.y = __float_as_int(-dinv[s] * dinv[d]);
        ew[pos] = v;
    }
}

// ---------------- conversions / weight prep ----------------

__global__ void cvtx_k(const float* __restrict__ x, unsigned short* __restrict__ Ab) {
    int i = blockIdx.x * blockDim.x + threadIdx.x;  // NN*16 groups of 8 feats
    if (i >= NN * 16) return;
    int row = i >> 4, cg = i & 15;
    const float4* xp = (const float4*)(x + (size_t)row * FDIM + cg * 8);
    float4 v0 = xp[0], v1 = xp[1];
    ushort8v r;
    r[0] = f2b(v0.x); r[1] = f2b(v0.y); r[2] = f2b(v0.z); r[3] = f2b(v0.w);
    r[4] = f2b(v1.x); r[5] = f2b(v1.y); r[6] = f2b(v1.z); r[7] = f2b(v1.w);
    *(ushort8v*)(Ab + (size_t)row * AW + cg * 8) = r;
}

// Fragment-major W for hid layers: idx = (((c*8+nt)*4+kcl)*64+l)*8+j
// k = c*128 + kcl*32 + (l>>4)*8 + j ; col = nt*16 + (l&15) ; v = W[c][k&127][col]
__global__ void wprep_hid_k(const float* __restrict__ W, unsigned short* __restrict__ Wfm) {
    int i = blockIdx.x * blockDim.x + threadIdx.x;  // 65536
    if (i >= 128 * AW) return;
    int j = i & 7, l = (i >> 3) & 63, kcl = (i >> 9) & 3, nt = (i >> 11) & 7, c = i >> 14;
    int r = kcl * 32 + (l >> 4) * 8 + j;
    int col = nt * 16 + (l & 15);
    Wfm[i] = f2b(W[((size_t)c * 128 + r) * 128 + col]);
}

// Fragment-major W for out layer (CLS padded to 48): idx = ((nt*16+kc)*64+l)*8+j
__global__ void wprep_out_k(const float* __restrict__ W, unsigned short* __restrict__ Wfm) {
    int i = blockIdx.x * blockDim.x + threadIdx.x;  // 24576
    if (i >= 48 * AW) return;
    int j = i & 7, l = (i >> 3) & 63, kc = (i >> 9) & 15, nt = i >> 13;
    int k = kc * 32 + (l >> 4) * 8 + j;
    int col = nt * 16 + (l & 15);
    int c = k >> 7, r = k & 127;
    float v = (col < CLS) ? W[((size_t)c * 128 + r) * CLS + col] : 0.0f;
    Wfm[i] = f2b(v);
}

// ---------------- SpMM (bf16 gather, fp32 accum, unroll 4) ----------------

template <bool CHEB>
__global__ __launch_bounds__(256) void spmm_k(const unsigned short* __restrict__ inp,
                                              const unsigned short* __restrict__ prevp,
                                              unsigned short* __restrict__ outp,
                                              const int* __restrict__ rp,
                                              const int2* __restrict__ ew) {
    int row = blockIdx.x * 16 + (threadIdx.x >> 4);
    int ln = threadIdx.x & 15;
    int e0 = rp[row], e1 = rp[row + 1];
    float acc[8] = {0.f, 0.f, 0.f, 0.f, 0.f, 0.f, 0.f, 0.f};
    int e = e0;
    for (; e + 4 <= e1; e += 4) {
        int2 m0 = ew[e], m1 = ew[e + 1], m2 = ew[e + 2], m3 = ew[e + 3];
        ushort8v t0 = *(const ushort8v*)(inp + (size_t)m0.x * AW + ln * 8);
        ushort8v t1 = *(const ushort8v*)(inp + (size_t)m1.x * AW + ln * 8);
        ushort8v t2 = *(const ushort8v*)(inp + (size_t)m2.x * AW + ln * 8);
        ushort8v t3 = *(const ushort8v*)(inp + (size_t)m3.x * AW + ln * 8);
        float w0 = __int_as_float(m0.y), w1 = __int_as_float(m1.y);
        float w2 = __int_as_float(m2.y), w3 = __int_as_float(m3.y);
        #pragma unroll
        for (int j = 0; j < 8; j++)
            acc[j] += w0 * b2f(t0[j]) + w1 * b2f(t1[j]) + w2 * b2f(t2[j]) + w3 * b2f(t3[j]);
    }
    for (; e < e1; e++) {
        int2 m0 = ew[e];
        ushort8v t0 = *(const ushort8v*)(inp + (size_t)m0.x * AW + ln * 8);
        float w0 = __int_as_float(m0.y);
        #pragma unroll
        for (int j = 0; j < 8; j++) acc[j] += w0 * b2f(t0[j]);
    }
    ushort8v r;
    if (CHEB) {
        ushort8v p = *(const ushort8v*)(prevp + (size_t)row * AW + ln * 8);
        #pragma unroll
        for (int j = 0; j < 8; j++) r[j] = f2b(2.f * acc[j] - b2f(p[j]));
    } else {
        #pragma unroll
        for (int j = 0; j < 8; j++) r[j] = f2b(acc[j]);
    }
    *(ushort8v*)(outp + (size_t)row * AW + ln * 8) = r;
}

// ---------------- MFMA GEMM, B staged in LDS (fragment-major) ----------------
// Block: 256 thr / 4 waves, 64 rows. K=512 in 4 chunks of 128.
// Per chunk: B chunk (32KB) memcpy'd to LDS; A frags prefetched 1 chunk ahead.

__global__ __launch_bounds__(256) void gemm_hid_k(const unsigned short* __restrict__ A,
                                                  const unsigned short* __restrict__ Wfm,
                                                  const float* __restrict__ bias,
                                                  unsigned short* __restrict__ Hout) {
    __shared__ unsigned short Blds[16384];  // 32KB
    int tid = threadIdx.x;
    int w = tid >> 6, lane = tid & 63, ln = lane & 15, gp = lane >> 4;
    int rowbase = blockIdx.x * 64 + w * 16;
    int rowc = rowbase + ln;
    if (rowc >= NN) rowc = NN - 1;  // clamp (stores guarded); never early-return (barriers!)
    const unsigned short* Arow = A + (size_t)rowc * AW + gp * 8;

    f32x4 acc[8];
    #pragma unroll
    for (int i = 0; i < 8; i++) acc[i] = (f32x4){0.f, 0.f, 0.f, 0.f};

    short8v acur[4], anxt[4];
    #pragma unroll
    for (int kcl = 0; kcl < 4; kcl++) acur[kcl] = *(const short8v*)(Arow + kcl * 32);
    {
        const ushort8v* g = (const ushort8v*)Wfm;
        ushort8v* s = (ushort8v*)Blds;
        #pragma unroll
        for (int i = 0; i < 8; i++) s[tid + i * 256] = g[tid + i * 256];
    }
    __syncthreads();

    for (int c = 0; c < 4; c++) {
        if (c < 3) {
            #pragma unroll
            for (int kcl = 0; kcl < 4; kcl++)
                anxt[kcl] = *(const short8v*)(Arow + (c + 1) * 128 + kcl * 32);
        }
        #pragma unroll
        for (int kcl = 0; kcl < 4; kcl++) {
            #pragma unroll
            for (int nt = 0; nt < 8; nt++) {
                short8v b = *(const short8v*)&Blds[((nt * 4 + kcl) * 64 + lane) * 8];
                acc[nt] = __builtin_amdgcn_mfma_f32_16x16x32_bf16(acur[kcl], b, acc[nt], 0, 0, 0);
            }
        }
        if (c < 3) {
            __syncthreads();
            const ushort8v* g = (const ushort8v*)(Wfm + (c + 1) * 16384);
            ushort8v* s = (ushort8v*)Blds;
            #pragma unroll
            for (int i = 0; i < 8; i++) s[tid + i * 256] = g[tid + i * 256];
            __syncthreads();
            #pragma unroll
            for (int kcl = 0; kcl < 4; kcl++) acur[kcl] = anxt[kcl];
        }
    }

    if (rowbase < NN) {
        #pragma unroll
        for (int nt = 0; nt < 8; nt++) {
            int col = nt * 16 + ln;
            float bv = bias[col];
            #pragma unroll
            for (int j = 0; j < 4; j++) {
                int r = rowbase + gp * 4 + j;
                Hout[(size_t)r * AW + col] = f2b(fmaxf(acc[nt][j] + bv, 0.0f));
            }
        }
    }
}

// out layer: 48 cols (40 valid), whole B (48KB) staged once; log_softmax fused.
__global__ __launch_bounds__(256) void gemm_out_k(const unsigned short* __restrict__ A,
                                                  const unsigned short* __restrict__ Wfm,
                                                  const float* __restrict__ bias,
                                                  float* __restrict__ outb) {
    __shared__ unsigned short Blds[24576];  // 48KB
    int tid = threadIdx.x;
    int w = tid >> 6, lane = tid & 63, ln = lane & 15, gp = lane >> 4;
    int rowbase = blockIdx.x * 64 + w * 16;
    int rowc = rowbase + ln;
    if (rowc >= NN) rowc = NN - 1;
    const unsigned short* Arow = A + (size_t)rowc * AW + gp * 8;

    f32x4 acc[3];
    #pragma unroll
    for (int i = 0; i < 3; i++) acc[i] = (f32x4){0.f, 0.f, 0.f, 0.f};

    {
        const ushort8v* g = (const ushort8v*)Wfm;
        ushort8v* s = (ushort8v*)Blds;
        #pragma unroll
        for (int i = 0; i < 12; i++) s[tid + i * 256] = g[tid + i * 256];
    }
    short8v a0 = *(const short8v*)(Arow);
    short8v a1 = *(const short8v*)(Arow + 32);
    __syncthreads();

    #pragma unroll
    for (int kc = 0; kc < 16; kc++) {
        short8v a = (kc & 1) ? a1 : a0;
        if (kc < 14) {
            if (kc & 1) a1 = *(const short8v*)(Arow + (kc + 2) * 32);
            else        a0 = *(const short8v*)(Arow + (kc + 2) * 32);
        }
        #pragma unroll
        for (int nt = 0; nt < 3; nt++) {
            short8v b = *(const short8v*)&Blds[((nt * 16 + kc) * 64 + lane) * 8];
            acc[nt] = __builtin_amdgcn_mfma_f32_16x16x32_bf16(a, b, acc[nt], 0, 0, 0);
        }
    }

    float b0v = bias[ln], b1v = bias[16 + ln];
    float b2v = (ln < 8) ? bias[32 + ln] : 0.0f;
    #pragma unroll
    for (int j = 0; j < 4; j++) {
        int r = rowbase + gp * 4 + j;
        float v0 = acc[0][j] + b0v;
        float v1 = acc[1][j] + b1v;
        float v2 = (ln < 8) ? (acc[2][j] + b2v) : -INFINITY;
        float m = fmaxf(fmaxf(v0, v1), v2);
        #pragma unroll
        for (int off = 8; off >= 1; off >>= 1) m = fmaxf(m, __shfl_xor(m, off));
        float s = __expf(v0 - m) + __expf(v1 - m) + ((ln < 8) ? __expf(v2 - m) : 0.0f);
        #pragma unroll
        for (int off = 8; off >= 1; off >>= 1) s += __shfl_xor(s, off);
        float ls = logf(s) + m;
        if (rowbase < NN) {
            outb[(size_t)r * CLS + ln] = v0 - ls;
            outb[(size_t)r * CLS + 16 + ln] = v1 - ls;
            if (ln < 8) outb[(size_t)r * CLS + 32 + ln] = v2 - ls;
        }
    }
}

// ---------------- launch ----------------

extern "C" void kernel_launch(void* const* d_in, const int* in_sizes, int n_in,
                              void* d_out, int out_size, void* d_ws, size_t ws_size,
                              hipStream_t stream) {
    const float* x    = (const float*)d_in[0];
    const int*   esrc = (const int*)d_in[1];
    const int*   edst = (const int*)d_in[2];
    const float* W0   = (const float*)d_in[3];
    const float* b0   = (const float*)d_in[4];
    const float* W1   = (const float*)d_in[5];
    const float* b1   = (const float*)d_in[6];
    const float* W2   = (const float*)d_in[7];
    const float* b2   = (const float*)d_in[8];
    float* out = (float*)d_out;

    char* p = (char*)d_ws;
    auto alloc = [&](size_t bytes) -> void* {
        void* r = (void*)p;
        p += (bytes + 255) & ~(size_t)255;
        return r;
    };
    unsigned short* Abuf = (unsigned short*)alloc((size_t)NN * AW * 2);   // 51.2 MB
    unsigned short* Wt0  = (unsigned short*)alloc((size_t)128 * AW * 2);
    unsigned short* Wt1  = (unsigned short*)alloc((size_t)128 * AW * 2);
    unsigned short* Wt2  = (unsigned short*)alloc((size_t)48 * AW * 2);
    int*   degi = (int*)alloc(NN * 4);
    int*   cnt  = (int*)alloc(NN * 4);
    float* dinv = (float*)alloc(NN * 4);
    int*   rp   = (int*)alloc((NN + 1) * 4);
    int*   bsum = (int*)alloc(SCAN_NB * 4);
    int2*  ew   = (int2*)alloc((size_t)NE * 8);

    const int TB = 256;
    int gN = (NN + TB - 1) / TB;
    int gE = (NE + TB - 1) / TB;
    int gE4 = (NE / 4 + TB - 1) / TB;

    zero_k<<<gN, TB, 0, stream>>>(degi, cnt);
    count_k<<<gE4, TB, 0, stream>>>((const int4*)esrc, (const int4*)edst, degi, cnt);
    dinv_k<<<gN, TB, 0, stream>>>(degi, dinv);
    scanA_k<<<SCAN_NB, TB, 0, stream>>>(cnt, bsum);
    scanB_k<<<1, 64, 0, stream>>>(bsum, rp);
    scanC_k<<<SCAN_NB, TB, 0, stream>>>(cnt, bsum, rp);
    scatter_k<<<gE, TB, 0, stream>>>(esrc, edst, rp, cnt, dinv, ew);

    cvtx_k<<<(NN * 16 + TB - 1) / TB, TB, 0, stream>>>(x, Abuf);
    wprep_hid_k<<<(128 * AW) / TB, TB, 0, stream>>>(W0, Wt0);
    wprep_hid_k<<<(128 * AW) / TB, TB, 0, stream>>>(W1, Wt1);
    wprep_out_k<<<(48 * AW) / TB, TB, 0, stream>>>(W2, Wt2);

    int gSpmm = (NN + 15) / 16;   // 3125
    int gGemm = (NN + 63) / 64;   // 782

    unsigned short* s0 = Abuf + 0 * 128;
    unsigned short* s1 = Abuf + 1 * 128;
    unsigned short* s2 = Abuf + 2 * 128;
    unsigned short* s3 = Abuf + 3 * 128;

    for (int l = 0; l < 3; l++) {
        spmm_k<false><<<gSpmm, TB, 0, stream>>>(s0, nullptr, s1, rp, ew);
        spmm_k<true><<<gSpmm, TB, 0, stream>>>(s1, s0, s2, rp, ew);
        spmm_k<true><<<gSpmm, TB, 0, stream>>>(s2, s1, s3, rp, ew);
        if (l < 2) {
            const unsigned short* Wt = (l == 0) ? Wt0 : Wt1;
            const float* bl = (l == 0) ? b0 : b1;
            gemm_hid_k<<<gGemm, TB, 0, stream>>>(Abuf, Wt, bl, Abuf);  // relu'd h -> slice 0
        } else {
            gemm_out_k<<<gGemm, TB, 0, stream>>>(Abuf, Wt2, b2, out);  // + fused log_softmax
        }
    }
}